// Round 7
// baseline (77.648 us; speedup 1.0000x reference)
//
#include <hip/hip_runtime.h>
#include <hip/hip_bf16.h>

// SpatialAttention2D MFMA v6b: B=2, C=64, N=4096, 4 heads x d=16, fp32 io.
// v6 with the compile fix: pack4_bf16 extracts bits via __builtin_memcpy
// (bit_cast rejects non-trivially-copyable __hip_bfloat162).
// (1) in-block key-split: waves 0,1 do keys 0..2047, waves 2,3 do
//     2048..4095 for the same 32 q; combine via tiny LDS epilogue ->
//     1024 blocks, 16 waves/CU (4/SIMD), no extra HBM traffic;
// (2) bank-swizzled tile layout (write+read identical XOR, bijective);
// (3) packed bf16 cvt; qkv drops LDS staging (wave-uniform x -> s-loads).

#define NTOK 4096
#define HD   16
#define BH   8
#define KT   256               // keys per LDS tile (per half)
#define CHUNKS (KT/16)         // 16 chunks = 8 even/odd pairs per stage
#define HALFK 2048             // keys per wave-pair
#define NSTAGE (HALFK/KT)      // 8

typedef __attribute__((ext_vector_type(4))) short short4v;
typedef __attribute__((ext_vector_type(4))) float float4v;
typedef __attribute__((ext_vector_type(4))) ushort ushort4v;
typedef __attribute__((ext_vector_type(2))) unsigned uint2v;

__device__ __forceinline__ ushort f2bf(float f) {
  unsigned u = __builtin_bit_cast(unsigned, f);
  u += 0x7fffu + ((u >> 16) & 1u);          // round-to-nearest-even
  return (ushort)(u >> 16);
}

__device__ __forceinline__ float fast_exp2(float x) {
#if __has_builtin(__builtin_amdgcn_exp2f)
  return __builtin_amdgcn_exp2f(x);
#else
  return exp2f(x);
#endif
}

// packed f32x4 -> bf16x4 (RNE), via compiler intrinsic (v_cvt_pk_bf16_f32)
__device__ __forceinline__ short4v pack4_bf16(float a, float b, float c, float d) {
  __hip_bfloat162 lo = __float22bfloat162_rn(make_float2(a, b));
  __hip_bfloat162 hi = __float22bfloat162_rn(make_float2(c, d));
  unsigned ulo, uhi;
  __builtin_memcpy(&ulo, &lo, 4);
  __builtin_memcpy(&uhi, &hi, 4);
  uint2v u = { ulo, uhi };
  return __builtin_bit_cast(short4v, u);
}

// bank swizzle within a 512B chunk row: fold byte bits [8:7] into [4:3].
// Applied identically at write and read -> bijective -> correctness-safe.
__device__ __forceinline__ int swzL(int L) { return L ^ (((L >> 7) & 3) << 3); }

// ws layout in ushort elements (3 MB total)
#define QB_OFF 0
#define KB_OFF ((size_t)BH*NTOK*HD)
#define VT_OFF (2*(size_t)BH*NTOK*HD)

// ---------------------------------------------------------------------------
// Kernel 1: QKV projection, no LDS. x addresses are wave-uniform -> compiler
// emits scalar loads (SMEM pipe), freeing VALU/LDS. One output channel per
// thread, 8 tokens per block. q scaled by 0.25*log2(e); V written transposed.
// ---------------------------------------------------------------------------
__global__ __launch_bounds__(192) void qkv_proj(
    const float* __restrict__ x, const float* __restrict__ w,
    const float* __restrict__ bias, ushort* __restrict__ wsu) {
  const int TOK = 8;
  int blk = blockIdx.x;            // 2 * 4096/8 = 1024
  int b   = blk >> 9;
  int n0  = (blk & 511) * TOK;
  int o   = threadIdx.x;           // 0..191

  float wr[64];
  const float4* w4 = reinterpret_cast<const float4*>(w + o*64);
  #pragma unroll
  for (int i = 0; i < 16; ++i) {
    float4 tt = w4[i];
    wr[4*i+0]=tt.x; wr[4*i+1]=tt.y; wr[4*i+2]=tt.z; wr[4*i+3]=tt.w;
  }
  float bb = bias[o];

  const float* xb = x + ((size_t)b*64)*NTOK + n0;   // wave-uniform

  float a[TOK];
  #pragma unroll
  for (int j = 0; j < TOK; ++j) a[j] = bb;

  #pragma unroll 8
  for (int c = 0; c < 64; ++c) {
    float wv = wr[c];
    const float* xc = xb + (size_t)c*NTOK;
    #pragma unroll
    for (int j = 0; j < TOK; ++j)
      a[j] = fmaf(xc[j], wv, a[j]);
  }

  int part = o >> 6;               // 0=q,1=k,2=v
  int oo   = o & 63;
  int h    = oo >> 4;
  int dd   = oo & 15;
  int bh   = b*4 + h;
  const float QSCALE = 0.25f * 1.44269504f;

  ushort* Qb = wsu + QB_OFF;
  ushort* Kb = wsu + KB_OFF;
  ushort* Vt = wsu + VT_OFF;

  if (part == 0) {
    #pragma unroll
    for (int j = 0; j < TOK; ++j)
      Qb[((size_t)bh*NTOK + n0 + j)*HD + dd] = f2bf(a[j]*QSCALE);
  } else if (part == 1) {
    #pragma unroll
    for (int j = 0; j < TOK; ++j)
      Kb[((size_t)bh*NTOK + n0 + j)*HD + dd] = f2bf(a[j]);
  } else {
    ushort4v v0 = { f2bf(a[0]), f2bf(a[1]), f2bf(a[2]), f2bf(a[3]) };
    ushort4v v1 = { f2bf(a[4]), f2bf(a[5]), f2bf(a[6]), f2bf(a[7]) };
    *(ushort4v*)(Vt + ((size_t)bh*HD + dd)*NTOK + n0    ) = v0;
    *(ushort4v*)(Vt + ((size_t)bh*HD + dd)*NTOK + n0 + 4) = v1;
  }
}

// ---------------------------------------------------------------------------
// Kernel 2: MFMA flash attention. Grid = 8 bh x 128 qblk = 1024 blocks.
// Block = 4 waves over 32 q: wave w -> q-group (w&1), key-half (w>>1).
// Tiles (per half): K 8KB + V 8KB, fragment-ordered + bank-swizzled.
// Epilogue combines the two key-halves per q-group through LDS.
// ---------------------------------------------------------------------------
__global__ __launch_bounds__(256, 4) void attn_mfma(
    const ushort* __restrict__ wsu, float* __restrict__ out) {
  const ushort* Qb = wsu + QB_OFF;
  const ushort* Kb = wsu + KB_OFF;
  const ushort* Vt = wsu + VT_OFF;

  int bh   = blockIdx.x >> 7;
  int qblk = blockIdx.x & 127;
  int tid  = threadIdx.x;
  int wid  = tid >> 6;
  int lane = tid & 63;
  int lr   = lane & 15;
  int g4   = (lane >> 4) << 2;
  int qg   = wid & 1;
  int half = wid >> 1;
  int qbase = qblk*32 + qg*16;

  __shared__ short4v Ksw[2][CHUNKS*64];   // 2 x 8 KB (per key-half)
  __shared__ short4v Vsw[2][CHUNKS*64];   // 2 x 8 KB
  __shared__ float  comb[2][64][6];       // epilogue combine, 3 KB

  const ushort* Kh = Kb + (size_t)bh*NTOK*HD;
  const ushort* Vh = Vt + (size_t)bh*HD*NTOK;
  const ushort* Qh = Qb + (size_t)bh*NTOK*HD;

  // Q fragment (B operand): lane l holds Q[q=l&15][d=g4..g4+3]
  short4v qf = *(const short4v*)(Qh + (size_t)(qbase + lr)*HD + g4);

  float4v acc_e = {0.f,0.f,0.f,0.f}, acc_o = {0.f,0.f,0.f,0.f};
  float le = 0.f, lo_ = 0.f;

  // ---- staging decomposition (v5-verified formulas), same for both halves.
  int ik0 = tid, ik1 = tid + 256;
  int kk0 = ik0 >> 1, kh0 = (ik0 & 1) * 8;
  int kk1 = ik1 >> 1, kh1 = (ik1 & 1) * 8;
  int kc0 = kk0 >> 4, ks0 = (kh0 >> 2)*16 + (kk0 & 15);
  int kc1 = kk1 >> 4, ks1 = (kh1 >> 2)*16 + (kk1 & 15);
  int vr0 = ik0 >> 5, vc0 = (ik0 & 31) * 8;
  int vr1 = ik1 >> 5, vc1 = (ik1 & 31) * 8;
  int vcc0 = vc0 >> 4, vs0 = ((vc0 & 15) >> 2)*16 + vr0;
  int vcc1 = vc1 >> 4, vs1 = ((vc1 & 15) >> 2)*16 + vr1;

  // swizzled LDS write byte-addresses (same within-array layout both halves)
  int kw0a = kc0*512 + (swzL(ks0*8      ) ^ ((kc0 & 3) << 5));
  int kw0b = kc0*512 + (swzL(ks0*8 + 128) ^ ((kc0 & 3) << 5));
  int kw1a = kc1*512 + (swzL(ks1*8      ) ^ ((kc1 & 3) << 5));
  int kw1b = kc1*512 + (swzL(ks1*8 + 128) ^ ((kc1 & 3) << 5));
  int vw0a = vcc0*512 + (swzL(vs0*8      ) ^ ((vcc0 & 3) << 5));
  int vw0b = vcc0*512 + (swzL(vs0*8 + 128) ^ ((vcc0 & 3) << 5));
  int vw1a = vcc1*512 + (swzL(vs1*8      ) ^ ((vcc1 & 3) << 5));
  int vw1b = vcc1*512 + (swzL(vs1*8 + 128) ^ ((vcc1 & 3) << 5));

  char* k0B = (char*)&Ksw[0][0];
  char* k1B = (char*)&Ksw[1][0];
  char* v0B = (char*)&Vsw[0][0];
  char* v1B = (char*)&Vsw[1][0];
  char* kbR = (char*)&Ksw[half][0];       // this wave's read bases
  char* vbR = (char*)&Vsw[half][0];

  // swizzled read byte-offsets, per chunk&3 variant
  int rbase = (lane << 3) ^ (((lane >> 4) & 3) << 3);
  int rb0 = rbase, rb1 = rbase ^ 32, rb2 = rbase ^ 64, rb3 = rbase ^ 96;

  uint4 pkA0, pkA1, pkB0, pkB1, pvA0, pvA1, pvB0, pvB1;

#define LOAD_STAGE(kb0n, kb1n)                                              \
  pkA0 = *(const uint4*)(Kh + (size_t)((kb0n) + kk0)*HD + kh0);             \
  pkA1 = *(const uint4*)(Kh + (size_t)((kb0n) + kk1)*HD + kh1);             \
  pkB0 = *(const uint4*)(Kh + (size_t)((kb1n) + kk0)*HD + kh0);             \
  pkB1 = *(const uint4*)(Kh + (size_t)((kb1n) + kk1)*HD + kh1);             \
  pvA0 = *(const uint4*)(Vh + (size_t)vr0*NTOK + (kb0n) + vc0);             \
  pvA1 = *(const uint4*)(Vh + (size_t)vr1*NTOK + (kb0n) + vc1);             \
  pvB0 = *(const uint4*)(Vh + (size_t)vr0*NTOK + (kb1n) + vc0);             \
  pvB1 = *(const uint4*)(Vh + (size_t)vr1*NTOK + (kb1n) + vc1);

#define ST2(base, a0, a1, q4) do {                                          \
    uint2v t0_ = {(q4).x, (q4).y}, t1_ = {(q4).z, (q4).w};                  \
    *(uint2v*)((base) + (a0)) = t0_;                                        \
    *(uint2v*)((base) + (a1)) = t1_; } while (0)

#define WRITE_STAGE()                                                       \
  ST2(k0B, kw0a, kw0b, pkA0); ST2(k0B, kw1a, kw1b, pkA1);                   \
  ST2(k1B, kw0a, kw0b, pkB0); ST2(k1B, kw1a, kw1b, pkB1);                   \
  ST2(v0B, vw0a, vw0b, pvA0); ST2(v0B, vw1a, vw1b, pvA1);                   \
  ST2(v1B, vw0a, vw0b, pvB0); ST2(v1B, vw1a, vw1b, pvB1);

  // prologue: stage 0 for both halves
  LOAD_STAGE(0, HALFK)
  WRITE_STAGE()
  __syncthreads();

  for (int s = 0; s < NSTAGE; ++s) {
    if (s + 1 < NSTAGE) {          // T14: issue next-stage loads early
      LOAD_STAGE((s + 1)*KT, HALFK + (s + 1)*KT)
    }
    #pragma unroll
    for (int p = 0; p < CHUNKS/2; ++p) {
      int re = (p & 1) ? rb2 : rb0;      // chunk 2p:   (2p)&3
      int ro = (p & 1) ? rb3 : rb1;      // chunk 2p+1: (2p+1)&3
      short4v kf_e = *(const short4v*)(kbR + p*1024       + re);
      short4v kf_o = *(const short4v*)(kbR + p*1024 + 512 + ro);
      short4v vf_e = *(const short4v*)(vbR + p*1024       + re);
      short4v vf_o = *(const short4v*)(vbR + p*1024 + 512 + ro);
      float4v zero = {0.f,0.f,0.f,0.f};
      float4v se = __builtin_amdgcn_mfma_f32_16x16x16bf16_1k(kf_e, qf, zero, 0, 0, 0);
      float4v so = __builtin_amdgcn_mfma_f32_16x16x16bf16_1k(kf_o, qf, zero, 0, 0, 0);
      float pe0 = fast_exp2(se[0]), pe1 = fast_exp2(se[1]);
      float pe2 = fast_exp2(se[2]), pe3 = fast_exp2(se[3]);
      float po0 = fast_exp2(so[0]), po1 = fast_exp2(so[1]);
      float po2 = fast_exp2(so[2]), po3 = fast_exp2(so[3]);
      le  += (pe0 + pe1) + (pe2 + pe3);
      lo_ += (po0 + po1) + (po2 + po3);
      short4v pbe = pack4_bf16(pe0, pe1, pe2, pe3);
      short4v pbo = pack4_bf16(po0, po1, po2, po3);
      acc_e = __builtin_amdgcn_mfma_f32_16x16x16bf16_1k(vf_e, pbe, acc_e, 0, 0, 0);
      acc_o = __builtin_amdgcn_mfma_f32_16x16x16bf16_1k(vf_o, pbo, acc_o, 0, 0, 0);
    }
    __syncthreads();
    if (s + 1 < NSTAGE) {
      WRITE_STAGE()
      __syncthreads();
    }
  }

  // per-wave l total for q = lane&15 (lanes l^16, l^32 hold same q)
  float l = le + lo_;
  l += __shfl_xor(l, 16); l += __shfl_xor(l, 32);

  float a0 = acc_e[0] + acc_o[0];
  float a1 = acc_e[1] + acc_o[1];
  float a2 = acc_e[2] + acc_o[2];
  float a3 = acc_e[3] + acc_o[3];

  // combine key-halves: waves 2,3 publish; waves 0,1 reduce + store
  if (half == 1) {
    comb[qg][lane][0] = a0; comb[qg][lane][1] = a1;
    comb[qg][lane][2] = a2; comb[qg][lane][3] = a3;
    comb[qg][lane][4] = l;
  }
  __syncthreads();
  if (half == 0) {
    a0 += comb[qg][lane][0]; a1 += comb[qg][lane][1];
    a2 += comb[qg][lane][2]; a3 += comb[qg][lane][3];
    l  += comb[qg][lane][4];
    float inv = 1.0f / l;
    int b = bh >> 2, h = bh & 3;
    float* ob = out + ((size_t)(b*64 + h*16 + g4)) * NTOK;
    ob[          qbase + lr] = a0 * inv;
    ob[  NTOK  + qbase + lr] = a1 * inv;
    ob[2*NTOK  + qbase + lr] = a2 * inv;
    ob[3*NTOK  + qbase + lr] = a3 * inv;
  }
#undef LOAD_STAGE
#undef ST2
#undef WRITE_STAGE
}

extern "C" void kernel_launch(void* const* d_in, const int* in_sizes, int n_in,
                              void* d_out, int out_size, void* d_ws, size_t ws_size,
                              hipStream_t stream) {
  const float* x    = (const float*)d_in[0];   // (2,64,64,64)
  const float* w    = (const float*)d_in[1];   // (192,64)
  const float* bias = (const float*)d_in[2];   // (192,)
  float* out  = (float*)d_out;                 // (2,64,64,64)
  ushort* wsu = (ushort*)d_ws;                 // 3 MB used

  qkv_proj <<<1024, 192, 0, stream>>>(x, w, bias, wsu);
  attn_mfma<<<1024, 256, 0, stream>>>(wsu, out);
}

// Round 8
// 46.244 us; speedup vs baseline: 1.6791x; 1.6791x over previous
//
#include <hip/hip_runtime.h>
#include <hip/hip_bf16.h>

// SpatialAttention2D MFMA v7: B=2, C=64, N=4096, 4 heads x d=16, fp32 io.
// vs v6b (which spilled its 32 staging VGPRs -> 108 MB scratch writes):
// staging registers eliminated via global_load_lds (16B) with per-lane
// PERMUTED global source addresses + linear LDS dest (m173 pattern).
// LDS tile layout [chunk][dhalf][key] in 16B units is simultaneously
//  (a) contiguous-in-global for staging and (b) conflict-free for b64
//  fragment reads at c*512 + (l&15)*16 + (l>>4)*8.
// In-block key-split kept (4 waves: qg = wid&1, half = wid>>1), true LDS
// double-buffer, one barrier/stage. lsum computed by MFMA with an all-ones
// A fragment (matrix pipe is idle; kills 8 VALU adds/pair + all shuffles).

#define NTOK 4096
#define HD   16
#define BH   8
#define KT   128               // keys per stage per half
#define SCH  (KT/16)           // 8 chunks per stage
#define HALFK 2048             // keys per key-half
#define NSTAGE (HALFK/KT)      // 16

typedef __attribute__((ext_vector_type(4))) short short4v;
typedef __attribute__((ext_vector_type(4))) float float4v;
typedef __attribute__((ext_vector_type(4))) ushort ushort4v;
typedef __attribute__((ext_vector_type(2))) unsigned uint2v;

__device__ __forceinline__ ushort f2bf(float f) {
  unsigned u = __builtin_bit_cast(unsigned, f);
  u += 0x7fffu + ((u >> 16) & 1u);          // round-to-nearest-even
  return (ushort)(u >> 16);
}

__device__ __forceinline__ float fast_exp2(float x) {
#if __has_builtin(__builtin_amdgcn_exp2f)
  return __builtin_amdgcn_exp2f(x);
#else
  return exp2f(x);
#endif
}

// packed f32x4 -> bf16x4 (RNE) via v_cvt_pk_bf16_f32 (v6b-verified form)
__device__ __forceinline__ short4v pack4_bf16(float a, float b, float c, float d) {
  __hip_bfloat162 lo = __float22bfloat162_rn(make_float2(a, b));
  __hip_bfloat162 hi = __float22bfloat162_rn(make_float2(c, d));
  unsigned ulo, uhi;
  __builtin_memcpy(&ulo, &lo, 4);
  __builtin_memcpy(&uhi, &hi, 4);
  uint2v u = { ulo, uhi };
  return __builtin_bit_cast(short4v, u);
}

// ws layout in ushort elements (3 MB total)
#define QB_OFF 0
#define KB_OFF ((size_t)BH*NTOK*HD)
#define VT_OFF (2*(size_t)BH*NTOK*HD)

// ---------------------------------------------------------------------------
// Kernel 1: QKV projection (v5-verified). TOK=8, LDS float4 broadcast reads,
// 1024 blocks. q scaled by 0.25*log2(e); V written transposed.
// ---------------------------------------------------------------------------
__global__ __launch_bounds__(192) void qkv_proj(
    const float* __restrict__ x, const float* __restrict__ w,
    const float* __restrict__ bias, ushort* __restrict__ wsu) {
  const int TOK = 8;
  int blk = blockIdx.x;            // 2 * 4096/8 = 1024
  int b   = blk >> 9;
  int n0  = (blk & 511) * TOK;
  int o   = threadIdx.x;           // 0..191

  __shared__ float4 xs4[64][TOK/4];   // [64][2]
  const float4* x4 = reinterpret_cast<const float4*>(x);
  for (int idx = threadIdx.x; idx < 64*(TOK/4); idx += 192) {
    int c = idx >> 1, t4 = idx & 1;
    xs4[c][t4] = x4[((size_t)b*64 + c)*(NTOK/4) + (n0 >> 2) + t4];
  }

  float wr[64];
  const float4* w4 = reinterpret_cast<const float4*>(w + o*64);
  #pragma unroll
  for (int i = 0; i < 16; ++i) {
    float4 tt = w4[i];
    wr[4*i+0]=tt.x; wr[4*i+1]=tt.y; wr[4*i+2]=tt.z; wr[4*i+3]=tt.w;
  }
  float bb = bias[o];

  int part = o >> 6;               // 0=q,1=k,2=v
  int oo   = o & 63;
  int h    = oo >> 4;
  int dd   = oo & 15;
  int bh   = b*4 + h;
  const float QSCALE = 0.25f * 1.44269504f;

  ushort* Qb = wsu + QB_OFF;
  ushort* Kb = wsu + KB_OFF;
  ushort* Vt = wsu + VT_OFF;

  __syncthreads();

  #pragma unroll
  for (int t4 = 0; t4 < TOK/4; ++t4) {
    float a[4] = {bb, bb, bb, bb};
    #pragma unroll
    for (int c = 0; c < 64; ++c) {
      float4 xv = xs4[c][t4];
      float wv = wr[c];
      a[0] = fmaf(xv.x, wv, a[0]);
      a[1] = fmaf(xv.y, wv, a[1]);
      a[2] = fmaf(xv.z, wv, a[2]);
      a[3] = fmaf(xv.w, wv, a[3]);
    }
    if (part == 0) {
      #pragma unroll
      for (int j = 0; j < 4; ++j)
        Qb[((size_t)bh*NTOK + n0 + t4*4 + j)*HD + dd] = f2bf(a[j]*QSCALE);
    } else if (part == 1) {
      #pragma unroll
      for (int j = 0; j < 4; ++j)
        Kb[((size_t)bh*NTOK + n0 + t4*4 + j)*HD + dd] = f2bf(a[j]);
    } else {
      ushort4v vv = { f2bf(a[0]), f2bf(a[1]), f2bf(a[2]), f2bf(a[3]) };
      *(ushort4v*)(Vt + ((size_t)bh*HD + dd)*NTOK + n0 + t4*4) = vv;
    }
  }
}

// ---------------------------------------------------------------------------
// Kernel 2: MFMA flash attention. Grid = 8 bh x 128 qblk(32q) = 1024 blocks,
// 4 waves: wave(qg, half) computes q-group qg (16 q) x key-half half (2048 k).
// Staging: global_load_lds 16B, linear LDS dest, permuted global source.
//   K unit (key,dh) at byte c*512 + dh*256 + kk*16  (c=chunk, kk=key&15)
//   V unit (d,oc)  at byte p*1024 + oc*256 + d*16   (p=pair, oc=key octet)
// Frag read (both): base + c*512 + (l&15)*16 + (l>>4)*8  -> dense, no conflict.
// ---------------------------------------------------------------------------
__global__ __launch_bounds__(256, 4) void attn_mfma(
    const ushort* __restrict__ wsu, float* __restrict__ out) {
  const ushort* Qb = wsu + QB_OFF;
  const ushort* Kb = wsu + KB_OFF;
  const ushort* Vt = wsu + VT_OFF;

  int bh   = blockIdx.x >> 7;
  int qblk = blockIdx.x & 127;
  int tid  = threadIdx.x;
  int wid  = tid >> 6;
  int lane = tid & 63;
  int lr   = lane & 15;
  int g4   = (lane >> 4) << 2;
  int qg   = wid & 1;
  int half = wid >> 1;
  int qbase = qblk*32 + qg*16;

  __shared__ __align__(16) char tiles[2][2][2][4096]; // [dbuf][half][K=0/V=1]
  __shared__ float comb[2][64][5];                    // 35.3 KB total

  const ushort* Qh = Qb + (size_t)bh*NTOK*HD;
  const ushort* Kh = Kb + (size_t)bh*NTOK*HD + (size_t)half*HALFK*HD;
  const ushort* Vh = Vt + (size_t)bh*HD*NTOK + half*HALFK;

  // Q fragment (B operand): lane l holds Q[q=l&15][d=g4..g4+3]
  short4v qf = *(const short4v*)(Qh + (size_t)(qbase + lr)*HD + g4);

  // per-lane staging source offsets (ushort elems):
  // K instr i: lane -> key 32i + (l>>5)*16 + (l&15), d-half (l>>4)&1
  size_t kgoff = (size_t)((lane >> 5)*16 + (lane & 15))*HD + ((lane >> 4) & 1)*8;
  // V instr i: lane -> d row l&15, key octet l>>4 within 32-key pair i
  size_t vgoff = (size_t)(lane & 15)*NTOK + (lane >> 4)*8;

  // fragment read byte-offset within a tile
  int loff = ((lane >> 5) << 8) + ((lane & 15) << 4) + (((lane >> 4) & 1) << 3);

  const short4v one4 = {(short)0x3F80, (short)0x3F80, (short)0x3F80, (short)0x3F80};

  float4v acc_e = {0.f,0.f,0.f,0.f}, acc_o = {0.f,0.f,0.f,0.f};
  float4v lac_e = {0.f,0.f,0.f,0.f}, lac_o = {0.f,0.f,0.f,0.f};

#define GLL(g, l_) __builtin_amdgcn_global_load_lds(                        \
    (const __attribute__((address_space(1))) unsigned*)(g),                 \
    (__attribute__((address_space(3))) unsigned*)(l_), 16, 0, 0)

#define STAGE(buf, s) do {                                                  \
    if (qg == 0) {                                                          \
      const ushort* gs = Kh + (size_t)(s)*(KT*HD) + kgoff;                  \
      char* lb = &tiles[buf][half][0][0];                                   \
      GLL(gs, lb); GLL(gs+512, lb+1024);                                    \
      GLL(gs+1024, lb+2048); GLL(gs+1536, lb+3072);                         \
    } else {                                                                \
      const ushort* gs = Vh + (size_t)(s)*KT + vgoff;                       \
      char* lb = &tiles[buf][half][1][0];                                   \
      GLL(gs, lb); GLL(gs+32, lb+1024);                                     \
      GLL(gs+64, lb+2048); GLL(gs+96, lb+3072);                             \
    } } while (0)

#define COMPUTE(buf) do {                                                   \
    const char* kb = &tiles[buf][half][0][0];                               \
    const char* vb = &tiles[buf][half][1][0];                               \
    _Pragma("unroll")                                                       \
    for (int p = 0; p < SCH/2; ++p) {                                       \
      short4v kf_e = *(const short4v*)(kb + p*1024       + loff);           \
      short4v kf_o = *(const short4v*)(kb + p*1024 + 512 + loff);           \
      short4v vf_e = *(const short4v*)(vb + p*1024       + loff);           \
      short4v vf_o = *(const short4v*)(vb + p*1024 + 512 + loff);           \
      float4v zero = {0.f,0.f,0.f,0.f};                                     \
      float4v se = __builtin_amdgcn_mfma_f32_16x16x16bf16_1k(kf_e, qf, zero, 0,0,0); \
      float4v so = __builtin_amdgcn_mfma_f32_16x16x16bf16_1k(kf_o, qf, zero, 0,0,0); \
      float pe0 = fast_exp2(se[0]), pe1 = fast_exp2(se[1]);                 \
      float pe2 = fast_exp2(se[2]), pe3 = fast_exp2(se[3]);                 \
      float po0 = fast_exp2(so[0]), po1 = fast_exp2(so[1]);                 \
      float po2 = fast_exp2(so[2]), po3 = fast_exp2(so[3]);                 \
      short4v pbe = pack4_bf16(pe0, pe1, pe2, pe3);                         \
      short4v pbo = pack4_bf16(po0, po1, po2, po3);                         \
      acc_e = __builtin_amdgcn_mfma_f32_16x16x16bf16_1k(vf_e, pbe, acc_e, 0,0,0); \
      acc_o = __builtin_amdgcn_mfma_f32_16x16x16bf16_1k(vf_o, pbo, acc_o, 0,0,0); \
      lac_e = __builtin_amdgcn_mfma_f32_16x16x16bf16_1k(one4, pbe, lac_e, 0,0,0); \
      lac_o = __builtin_amdgcn_mfma_f32_16x16x16bf16_1k(one4, pbo, lac_o, 0,0,0); \
    } } while (0)

  // prologue: stage 0 (compiler drains vmcnt before the barrier)
  STAGE(0, 0);
  __syncthreads();

  #pragma unroll 1
  for (int s = 0; s < NSTAGE; s += 2) {
    if (s + 1 < NSTAGE) STAGE(1, s + 1);   // prefetch next stage -> buf 1
    COMPUTE(0);
    __syncthreads();
    if (s + 2 < NSTAGE) STAGE(0, s + 2);   // prefetch -> buf 0
    COMPUTE(1);
    __syncthreads();
  }

  // lsum: ones-MFMA left every lane holding l(q=l&15) in every reg; no shuffle
  float a0 = acc_e[0] + acc_o[0];
  float a1 = acc_e[1] + acc_o[1];
  float a2 = acc_e[2] + acc_o[2];
  float a3 = acc_e[3] + acc_o[3];
  float ls = lac_e[0] + lac_o[0];

  // combine key-halves: waves half=1 publish; half=0 reduce + store
  if (half == 1) {
    comb[qg][lane][0] = a0; comb[qg][lane][1] = a1;
    comb[qg][lane][2] = a2; comb[qg][lane][3] = a3;
    comb[qg][lane][4] = ls;
  }
  __syncthreads();
  if (half == 0) {
    a0 += comb[qg][lane][0]; a1 += comb[qg][lane][1];
    a2 += comb[qg][lane][2]; a3 += comb[qg][lane][3];
    ls += comb[qg][lane][4];
    float inv = 1.0f / ls;
    int b = bh >> 2, h = bh & 3;
    float* ob = out + ((size_t)(b*64 + h*16 + g4)) * NTOK;
    ob[           qbase + lr] = a0 * inv;
    ob[  NTOK   + qbase + lr] = a1 * inv;
    ob[2*NTOK   + qbase + lr] = a2 * inv;
    ob[3*NTOK   + qbase + lr] = a3 * inv;
  }
#undef GLL
#undef STAGE
#undef COMPUTE
}

extern "C" void kernel_launch(void* const* d_in, const int* in_sizes, int n_in,
                              void* d_out, int out_size, void* d_ws, size_t ws_size,
                              hipStream_t stream) {
  const float* x    = (const float*)d_in[0];   // (2,64,64,64)
  const float* w    = (const float*)d_in[1];   // (192,64)
  const float* bias = (const float*)d_in[2];   // (192,)
  float* out  = (float*)d_out;                 // (2,64,64,64)
  ushort* wsu = (ushort*)d_ws;                 // 3 MB used

  qkv_proj <<<1024, 192, 0, stream>>>(x, w, bias, wsu);
  attn_mfma<<<1024, 256, 0, stream>>>(wsu, out);
}

// Round 9
// 43.225 us; speedup vs baseline: 1.7963x; 1.0698x over previous
//
#include <hip/hip_runtime.h>
#include <hip/hip_bf16.h>

// SpatialAttention2D MFMA v8: B=2, C=64, N=4096, 4 heads x d=16, fp32 io.
// vs v7: qkv_proj rewritten for the A/B test of "qkv is the slow half":
//   - TILES=2 token-tiles per block (weights loaded once, amortized)
//   - Q stored TRANSPOSED [bh][d][n] -> vector ushort4 stores (like V);
//     K stays [n][d] (needed by the K-staging layout).
// attn_mfma: identical to v7 except (a) Q fragment read from transposed
// layout (4 scalar loads, once), (b) s_setprio(1) around the MFMA cluster.

#define NTOK 4096
#define HD   16
#define BH   8
#define KT   128               // keys per stage per half
#define SCH  (KT/16)           // 8 chunks per stage
#define HALFK 2048             // keys per key-half
#define NSTAGE (HALFK/KT)      // 16

typedef __attribute__((ext_vector_type(4))) short short4v;
typedef __attribute__((ext_vector_type(4))) float float4v;
typedef __attribute__((ext_vector_type(4))) ushort ushort4v;
typedef __attribute__((ext_vector_type(2))) unsigned uint2v;

__device__ __forceinline__ ushort f2bf(float f) {
  unsigned u = __builtin_bit_cast(unsigned, f);
  u += 0x7fffu + ((u >> 16) & 1u);          // round-to-nearest-even
  return (ushort)(u >> 16);
}

__device__ __forceinline__ float fast_exp2(float x) {
#if __has_builtin(__builtin_amdgcn_exp2f)
  return __builtin_amdgcn_exp2f(x);
#else
  return exp2f(x);
#endif
}

// packed f32x4 -> bf16x4 (RNE) via v_cvt_pk_bf16_f32 (v6b-verified form)
__device__ __forceinline__ short4v pack4_bf16(float a, float b, float c, float d) {
  __hip_bfloat162 lo = __float22bfloat162_rn(make_float2(a, b));
  __hip_bfloat162 hi = __float22bfloat162_rn(make_float2(c, d));
  unsigned ulo, uhi;
  __builtin_memcpy(&ulo, &lo, 4);
  __builtin_memcpy(&uhi, &hi, 4);
  uint2v u = { ulo, uhi };
  return __builtin_bit_cast(short4v, u);
}

// ws layout in ushort elements (3 MB total)
// Qt: [bh][d][n] (transposed!), Kb: [bh][n][d], Vt: [bh][d][n]
#define QB_OFF 0
#define KB_OFF ((size_t)BH*NTOK*HD)
#define VT_OFF (2*(size_t)BH*NTOK*HD)

// ---------------------------------------------------------------------------
// Kernel 1: QKV projection. 512 blocks x 192 threads, 2 tiles x 8 tokens.
// Weights in regs (loaded once). Q scaled by 0.25*log2(e), stored [d][n];
// V stored [d][n]; K stored [n][d].
// ---------------------------------------------------------------------------
__global__ __launch_bounds__(192) void qkv_proj(
    const float* __restrict__ x, const float* __restrict__ w,
    const float* __restrict__ bias, ushort* __restrict__ wsu) {
  const int TOK = 8, TILES = 2;
  int blk = blockIdx.x;            // 2 * 4096/16 = 512
  int b   = blk >> 8;
  int n00 = (blk & 255) * (TOK*TILES);
  int o   = threadIdx.x;           // 0..191

  float wr[64];
  const float4* w4 = reinterpret_cast<const float4*>(w + o*64);
  #pragma unroll
  for (int i = 0; i < 16; ++i) {
    float4 tt = w4[i];
    wr[4*i+0]=tt.x; wr[4*i+1]=tt.y; wr[4*i+2]=tt.z; wr[4*i+3]=tt.w;
  }
  float bb = bias[o];

  int part = o >> 6;               // 0=q,1=k,2=v
  int oo   = o & 63;
  int h    = oo >> 4;
  int dd   = oo & 15;
  int bh   = b*4 + h;
  const float QSCALE = 0.25f * 1.44269504f;

  ushort* Qt = wsu + QB_OFF;
  ushort* Kb = wsu + KB_OFF;
  ushort* Vt = wsu + VT_OFF;

  __shared__ float4 xs4[64][2];
  const float4* x4 = reinterpret_cast<const float4*>(x);

  #pragma unroll 1
  for (int tile = 0; tile < TILES; ++tile) {
    int n0 = n00 + tile*TOK;
    for (int idx = threadIdx.x; idx < 128; idx += 192) {
      int c = idx >> 1, t4 = idx & 1;
      xs4[c][t4] = x4[((size_t)b*64 + c)*(NTOK/4) + (n0 >> 2) + t4];
    }
    __syncthreads();

    #pragma unroll
    for (int t4 = 0; t4 < 2; ++t4) {
      float a[4] = {bb, bb, bb, bb};
      #pragma unroll
      for (int c = 0; c < 64; ++c) {
        float4 xv = xs4[c][t4];
        float wv = wr[c];
        a[0] = fmaf(xv.x, wv, a[0]);
        a[1] = fmaf(xv.y, wv, a[1]);
        a[2] = fmaf(xv.z, wv, a[2]);
        a[3] = fmaf(xv.w, wv, a[3]);
      }
      if (part == 0) {
        ushort4v vv = { f2bf(a[0]*QSCALE), f2bf(a[1]*QSCALE),
                        f2bf(a[2]*QSCALE), f2bf(a[3]*QSCALE) };
        *(ushort4v*)(Qt + ((size_t)bh*HD + dd)*NTOK + n0 + t4*4) = vv;
      } else if (part == 1) {
        #pragma unroll
        for (int j = 0; j < 4; ++j)
          Kb[((size_t)bh*NTOK + n0 + t4*4 + j)*HD + dd] = f2bf(a[j]);
      } else {
        ushort4v vv = { f2bf(a[0]), f2bf(a[1]), f2bf(a[2]), f2bf(a[3]) };
        *(ushort4v*)(Vt + ((size_t)bh*HD + dd)*NTOK + n0 + t4*4) = vv;
      }
    }
    __syncthreads();
  }
}

// ---------------------------------------------------------------------------
// Kernel 2: MFMA flash attention (v7 structure). Grid = 8 bh x 128 qblk = 1024
// blocks, 4 waves: wave(qg, half) = q-group qg (16 q) x key-half (2048 k).
// Staging via global_load_lds 16B, linear LDS dest, permuted global source.
// Q fragment from transposed Qt (4 scalar loads). setprio around MFMA.
// ---------------------------------------------------------------------------
__global__ __launch_bounds__(256, 4) void attn_mfma(
    const ushort* __restrict__ wsu, float* __restrict__ out) {
  const ushort* Qt = wsu + QB_OFF;
  const ushort* Kb = wsu + KB_OFF;
  const ushort* Vt = wsu + VT_OFF;

  int bh   = blockIdx.x >> 7;
  int qblk = blockIdx.x & 127;
  int tid  = threadIdx.x;
  int wid  = tid >> 6;
  int lane = tid & 63;
  int lr   = lane & 15;
  int g4   = (lane >> 4) << 2;
  int qg   = wid & 1;
  int half = wid >> 1;
  int qbase = qblk*32 + qg*16;

  __shared__ __align__(16) char tiles[2][2][2][4096]; // [dbuf][half][K=0/V=1]
  __shared__ float comb[2][64][5];                    // 35.3 KB total

  const ushort* Qh = Qt + (size_t)bh*NTOK*HD;         // [d][n]
  const ushort* Kh = Kb + (size_t)bh*NTOK*HD + (size_t)half*HALFK*HD;
  const ushort* Vh = Vt + (size_t)bh*HD*NTOK + half*HALFK;

  // Q fragment (B operand): lane l holds Q[q=l&15][d=g4..g4+3] from [d][n]
  short4v qf;
  qf[0] = (short)Qh[(size_t)(g4+0)*NTOK + qbase + lr];
  qf[1] = (short)Qh[(size_t)(g4+1)*NTOK + qbase + lr];
  qf[2] = (short)Qh[(size_t)(g4+2)*NTOK + qbase + lr];
  qf[3] = (short)Qh[(size_t)(g4+3)*NTOK + qbase + lr];

  // per-lane staging source offsets (ushort elems):
  size_t kgoff = (size_t)((lane >> 5)*16 + (lane & 15))*HD + ((lane >> 4) & 1)*8;
  size_t vgoff = (size_t)(lane & 15)*NTOK + (lane >> 4)*8;

  // fragment read byte-offset within a tile
  int loff = ((lane >> 5) << 8) + ((lane & 15) << 4) + (((lane >> 4) & 1) << 3);

  const short4v one4 = {(short)0x3F80, (short)0x3F80, (short)0x3F80, (short)0x3F80};

  float4v acc_e = {0.f,0.f,0.f,0.f}, acc_o = {0.f,0.f,0.f,0.f};
  float4v lac_e = {0.f,0.f,0.f,0.f}, lac_o = {0.f,0.f,0.f,0.f};

#define GLL(g, l_) __builtin_amdgcn_global_load_lds(                        \
    (const __attribute__((address_space(1))) unsigned*)(g),                 \
    (__attribute__((address_space(3))) unsigned*)(l_), 16, 0, 0)

#define STAGE(buf, s) do {                                                  \
    if (qg == 0) {                                                          \
      const ushort* gs = Kh + (size_t)(s)*(KT*HD) + kgoff;                  \
      char* lb = &tiles[buf][half][0][0];                                   \
      GLL(gs, lb); GLL(gs+512, lb+1024);                                    \
      GLL(gs+1024, lb+2048); GLL(gs+1536, lb+3072);                         \
    } else {                                                                \
      const ushort* gs = Vh + (size_t)(s)*KT + vgoff;                       \
      char* lb = &tiles[buf][half][1][0];                                   \
      GLL(gs, lb); GLL(gs+32, lb+1024);                                     \
      GLL(gs+64, lb+2048); GLL(gs+96, lb+3072);                             \
    } } while (0)

#define COMPUTE(buf) do {                                                   \
    const char* kb = &tiles[buf][half][0][0];                               \
    const char* vb = &tiles[buf][half][1][0];                               \
    __builtin_amdgcn_s_setprio(1);                                          \
    _Pragma("unroll")                                                       \
    for (int p = 0; p < SCH/2; ++p) {                                       \
      short4v kf_e = *(const short4v*)(kb + p*1024       + loff);           \
      short4v kf_o = *(const short4v*)(kb + p*1024 + 512 + loff);           \
      short4v vf_e = *(const short4v*)(vb + p*1024       + loff);           \
      short4v vf_o = *(const short4v*)(vb + p*1024 + 512 + loff);           \
      float4v zero = {0.f,0.f,0.f,0.f};                                     \
      float4v se = __builtin_amdgcn_mfma_f32_16x16x16bf16_1k(kf_e, qf, zero, 0,0,0); \
      float4v so = __builtin_amdgcn_mfma_f32_16x16x16bf16_1k(kf_o, qf, zero, 0,0,0); \
      float pe0 = fast_exp2(se[0]), pe1 = fast_exp2(se[1]);                 \
      float pe2 = fast_exp2(se[2]), pe3 = fast_exp2(se[3]);                 \
      float po0 = fast_exp2(so[0]), po1 = fast_exp2(so[1]);                 \
      float po2 = fast_exp2(so[2]), po3 = fast_exp2(so[3]);                 \
      short4v pbe = pack4_bf16(pe0, pe1, pe2, pe3);                         \
      short4v pbo = pack4_bf16(po0, po1, po2, po3);                         \
      acc_e = __builtin_amdgcn_mfma_f32_16x16x16bf16_1k(vf_e, pbe, acc_e, 0,0,0); \
      acc_o = __builtin_amdgcn_mfma_f32_16x16x16bf16_1k(vf_o, pbo, acc_o, 0,0,0); \
      lac_e = __builtin_amdgcn_mfma_f32_16x16x16bf16_1k(one4, pbe, lac_e, 0,0,0); \
      lac_o = __builtin_amdgcn_mfma_f32_16x16x16bf16_1k(one4, pbo, lac_o, 0,0,0); \
    }                                                                       \
    __builtin_amdgcn_s_setprio(0);                                          \
    } while (0)

  // prologue: stage 0 (compiler drains vmcnt before the barrier)
  STAGE(0, 0);
  __syncthreads();

  #pragma unroll 1
  for (int s = 0; s < NSTAGE; s += 2) {
    if (s + 1 < NSTAGE) STAGE(1, s + 1);   // prefetch next stage -> buf 1
    COMPUTE(0);
    __syncthreads();
    if (s + 2 < NSTAGE) STAGE(0, s + 2);   // prefetch -> buf 0
    COMPUTE(1);
    __syncthreads();
  }

  // lsum: ones-MFMA left every lane holding l(q=l&15) in every reg
  float a0 = acc_e[0] + acc_o[0];
  float a1 = acc_e[1] + acc_o[1];
  float a2 = acc_e[2] + acc_o[2];
  float a3 = acc_e[3] + acc_o[3];
  float ls = lac_e[0] + lac_o[0];

  // combine key-halves: waves half=1 publish; half=0 reduce + store
  if (half == 1) {
    comb[qg][lane][0] = a0; comb[qg][lane][1] = a1;
    comb[qg][lane][2] = a2; comb[qg][lane][3] = a3;
    comb[qg][lane][4] = ls;
  }
  __syncthreads();
  if (half == 0) {
    a0 += comb[qg][lane][0]; a1 += comb[qg][lane][1];
    a2 += comb[qg][lane][2]; a3 += comb[qg][lane][3];
    ls += comb[qg][lane][4];
    float inv = 1.0f / ls;
    int b = bh >> 2, h = bh & 3;
    float* ob = out + ((size_t)(b*64 + h*16 + g4)) * NTOK;
    ob[           qbase + lr] = a0 * inv;
    ob[  NTOK   + qbase + lr] = a1 * inv;
    ob[2*NTOK   + qbase + lr] = a2 * inv;
    ob[3*NTOK   + qbase + lr] = a3 * inv;
  }
#undef GLL
#undef STAGE
#undef COMPUTE
}

extern "C" void kernel_launch(void* const* d_in, const int* in_sizes, int n_in,
                              void* d_out, int out_size, void* d_ws, size_t ws_size,
                              hipStream_t stream) {
  const float* x    = (const float*)d_in[0];   // (2,64,64,64)
  const float* w    = (const float*)d_in[1];   // (192,64)
  const float* bias = (const float*)d_in[2];   // (192,)
  float* out  = (float*)d_out;                 // (2,64,64,64)
  ushort* wsu = (ushort*)d_ws;                 // 3 MB used

  qkv_proj <<<512,  192, 0, stream>>>(x, w, bias, wsu);
  attn_mfma<<<1024, 256, 0, stream>>>(wsu, out);
}